// Round 1
// baseline (2542.754 us; speedup 1.0000x reference)
//
#include <hip/hip_runtime.h>
#include <math.h>

#define NEGV (-1e9f)
constexpr int B = 32, S = 4096, K = 512, H = 512;

// ---------------- K1: qproj[head][b][h] = query[b] @ Wq_head ----------------
__global__ __launch_bounds__(512)
void qproj_kernel(const float* __restrict__ query,
                  const float* __restrict__ Wq_a,
                  const float* __restrict__ Wq_b,
                  float* __restrict__ qproj) {
  const int b = blockIdx.x, head = blockIdx.y;
  const float* __restrict__ Wq = head ? Wq_b : Wq_a;
  __shared__ float qs[H];
  qs[threadIdx.x] = query[b * H + threadIdx.x];
  __syncthreads();
  const int h = threadIdx.x;
  float acc = 0.f;
#pragma unroll 8
  for (int k = 0; k < H; ++k) acc = fmaf(qs[k], Wq[k * H + h], acc);
  qproj[(head * B + b) * H + h] = acc;
}

// ---------------- K2: scores[head][b][s] = mask ? v . tanh(qp + V[s,:]@Wk) : NEG
// f32 tiled GEMM: block = 256 thr, tile 64s x 64h, 4x4 micro, kc=32, fused tanh+v-dot.
__global__ __launch_bounds__(256)
void scores_kernel(const float* __restrict__ values_a, const float* __restrict__ values_b,
                   const float* __restrict__ Wk_a, const float* __restrict__ Wk_b,
                   const float* __restrict__ v_a, const float* __restrict__ v_b,
                   const int* __restrict__ mask_a, const int* __restrict__ mask_b,
                   const float* __restrict__ qproj,
                   float* __restrict__ scores) {
  const int head = blockIdx.z, b = blockIdx.y, s0 = blockIdx.x * 64;
  const float* __restrict__ V  = (head ? values_b : values_a) + (size_t)b * S * K;
  const float* __restrict__ Wk = head ? Wk_b : Wk_a;
  const float* __restrict__ v  = head ? v_b : v_a;
  const int*   __restrict__ mask = (head ? mask_b : mask_a) + b * S;
  const float* __restrict__ qp = qproj + (head * B + b) * H;

  __shared__ float Vs[32 * 64];   // [k][s]  (transposed for b128 reads)
  __shared__ float Ws[32 * 64];   // [k][h]
  __shared__ float red[16][65];

  const int tid = threadIdx.x;
  const int tx = tid & 15;          // h-group (4 cols)
  const int ty = tid >> 4;          // s-group (4 rows)
  const int vs_row = tid >> 2;      // 0..63 : s within tile
  const int vs_k   = (tid & 3) * 8; // 0..24 : k within chunk
  const int ws_row = tid >> 3;      // 0..31 : k within chunk
  const int ws_h   = (tid & 7) * 8; // 0..56 : h within chunk

  float sc[4] = {0.f, 0.f, 0.f, 0.f};

  for (int h0 = 0; h0 < H; h0 += 64) {
    float acc[4][4] = {};
    for (int k0 = 0; k0 < K; k0 += 32) {
      const float4 p0 = *(const float4*)(V + (size_t)(s0 + vs_row) * K + k0 + vs_k);
      const float4 p1 = *(const float4*)(V + (size_t)(s0 + vs_row) * K + k0 + vs_k + 4);
      const float4 q0 = *(const float4*)(Wk + (size_t)(k0 + ws_row) * H + h0 + ws_h);
      const float4 q1 = *(const float4*)(Wk + (size_t)(k0 + ws_row) * H + h0 + ws_h + 4);
      __syncthreads();
      Vs[(vs_k + 0) * 64 + vs_row] = p0.x;
      Vs[(vs_k + 1) * 64 + vs_row] = p0.y;
      Vs[(vs_k + 2) * 64 + vs_row] = p0.z;
      Vs[(vs_k + 3) * 64 + vs_row] = p0.w;
      Vs[(vs_k + 4) * 64 + vs_row] = p1.x;
      Vs[(vs_k + 5) * 64 + vs_row] = p1.y;
      Vs[(vs_k + 6) * 64 + vs_row] = p1.z;
      Vs[(vs_k + 7) * 64 + vs_row] = p1.w;
      *(float4*)(Ws + ws_row * 64 + ws_h)     = q0;
      *(float4*)(Ws + ws_row * 64 + ws_h + 4) = q1;
      __syncthreads();
#pragma unroll
      for (int kk = 0; kk < 32; ++kk) {
        const float4 av = *(const float4*)(Vs + kk * 64 + ty * 4);
        const float4 wv = *(const float4*)(Ws + kk * 64 + tx * 4);
        const float a[4] = {av.x, av.y, av.z, av.w};
        const float w[4] = {wv.x, wv.y, wv.z, wv.w};
#pragma unroll
        for (int i = 0; i < 4; ++i)
#pragma unroll
          for (int j = 0; j < 4; ++j)
            acc[i][j] = fmaf(a[i], w[j], acc[i][j]);
      }
    }
    const float4 qp4 = *(const float4*)(qp + h0 + tx * 4);
    const float4 v4  = *(const float4*)(v + h0 + tx * 4);
    const float qpw[4] = {qp4.x, qp4.y, qp4.z, qp4.w};
    const float vw[4]  = {v4.x, v4.y, v4.z, v4.w};
#pragma unroll
    for (int i = 0; i < 4; ++i)
#pragma unroll
      for (int j = 0; j < 4; ++j)
        sc[i] = fmaf(vw[j], tanhf(acc[i][j] + qpw[j]), sc[i]);
  }
  __syncthreads();
#pragma unroll
  for (int i = 0; i < 4; ++i) red[tx][ty * 4 + i] = sc[i];
  __syncthreads();
  if (tid < 64) {
    float tot = 0.f;
#pragma unroll
    for (int t = 0; t < 16; ++t) tot += red[t][tid];
    const int s = s0 + tid;
    scores[((size_t)head * B + b) * S + s] = mask[s] ? tot : NEGV;
  }
}

// ---------------- K3: sparsemax per (b, head) row via bisection + exact refine
__device__ __forceinline__ float block_reduce_1024(float v, float* lds, const bool is_max) {
#pragma unroll
  for (int o = 32; o > 0; o >>= 1) {
    const float other = __shfl_xor(v, o, 64);
    v = is_max ? fmaxf(v, other) : (v + other);
  }
  const int wid = threadIdx.x >> 6;
  __syncthreads();
  if ((threadIdx.x & 63) == 0) lds[wid] = v;
  __syncthreads();
  if (threadIdx.x == 0) {
    float r = lds[0];
    for (int w = 1; w < 16; ++w) r = is_max ? fmaxf(r, lds[w]) : (r + lds[w]);
    lds[0] = r;
  }
  __syncthreads();
  return lds[0];
}

__global__ __launch_bounds__(1024)
void sparsemax_kernel(const float* __restrict__ scores, float* __restrict__ d_out_f) {
  const int b = blockIdx.x, head = blockIdx.y;
  const float* __restrict__ z = scores + ((size_t)head * B + b) * S;
  float* __restrict__ alpha = d_out_f + B * H + (size_t)head * B * S + (size_t)b * S;
  __shared__ float lds[16];
  const int tid = threadIdx.x;
  float e[4];
#pragma unroll
  for (int t = 0; t < 4; ++t) e[t] = z[t * 1024 + tid];
  float m = fmaxf(fmaxf(e[0], e[1]), fmaxf(e[2], e[3]));
  m = block_reduce_1024(m, lds, true);
  // f(tau) = sum max(z - tau, 0) is decreasing; f(m-1) >= 1, f(m) = 0.
  float lo = m - 1.f, hi = m;
  for (int it = 0; it < 28; ++it) {
    const float mid = 0.5f * (lo + hi);
    float s = 0.f;
#pragma unroll
    for (int t = 0; t < 4; ++t) s += fmaxf(e[t] - mid, 0.f);
    s = block_reduce_1024(s, lds, false);
    if (s >= 1.f) lo = mid; else hi = mid;
  }
  // exact refinement on the (now-correct) support set {z > lo}
  float cnt = 0.f, sum = 0.f;
#pragma unroll
  for (int t = 0; t < 4; ++t) {
    if (e[t] > lo) { cnt += 1.f; sum += e[t]; }
  }
  cnt = block_reduce_1024(cnt, lds, false);
  sum = block_reduce_1024(sum, lds, false);
  const float tau = (sum - 1.f) / cnt;
#pragma unroll
  for (int t = 0; t < 4; ++t) alpha[t * 1024 + tid] = fmaxf(e[t] - tau, 0.f);
}

// ---------------- K4: context = alphas @ values, exploiting sparsemax sparsity
__global__ __launch_bounds__(512)
void context_kernel(const float* __restrict__ values_a, const float* __restrict__ values_b,
                    const float* __restrict__ d_out_f, float* __restrict__ ctx) {
  const int b = blockIdx.x, head = blockIdx.y;
  const float* __restrict__ V = (head ? values_b : values_a) + (size_t)b * S * K;
  const float* __restrict__ al = d_out_f + B * H + (size_t)head * B * S + (size_t)b * S;
  __shared__ int cnt;
  __shared__ int sidx[S];
  __shared__ float sal[S];
  if (threadIdx.x == 0) cnt = 0;
  __syncthreads();
  for (int i = threadIdx.x; i < S; i += 512) {
    const float a = al[i];
    if (a > 0.f) { const int p = atomicAdd(&cnt, 1); sidx[p] = i; sal[p] = a; }
  }
  __syncthreads();
  const int n = cnt;
  const int j = threadIdx.x;
  float acc = 0.f;
  for (int t = 0; t < n; ++t) acc = fmaf(sal[t], V[(size_t)sidx[t] * K + j], acc);
  ctx[(head * B + b) * K + j] = acc;
}

// ---------------- K5: gate + candidates + output merge, one block per batch
__global__ __launch_bounds__(512)
void merge_kernel(const float* __restrict__ query, const float* __restrict__ ctx,
                  const float* __restrict__ Wg, const float* __restrict__ bg,
                  const float* __restrict__ Wu_a, const float* __restrict__ bu_a,
                  const float* __restrict__ Wu_b, const float* __restrict__ bu_b,
                  float* __restrict__ att) {
  const int b = blockIdx.x;
  __shared__ float gin[1536];   // [q | ctx_a | ctx_b]
  __shared__ float lred[16];
  __shared__ float gw[2];
  const int tid = threadIdx.x;
  gin[tid]        = query[b * H + tid];
  gin[512 + tid]  = ctx[(0 * B + b) * K + tid];
  gin[1024 + tid] = ctx[(1 * B + b) * K + tid];
  __syncthreads();
  float p0 = 0.f, p1 = 0.f;
  for (int i = tid; i < 1536; i += 512) {
    const float x = gin[i];
    p0 = fmaf(x, Wg[i * 2 + 0], p0);
    p1 = fmaf(x, Wg[i * 2 + 1], p1);
  }
#pragma unroll
  for (int o = 32; o > 0; o >>= 1) { p0 += __shfl_xor(p0, o, 64); p1 += __shfl_xor(p1, o, 64); }
  if ((tid & 63) == 0) { lred[tid >> 6] = p0; lred[8 + (tid >> 6)] = p1; }
  __syncthreads();
  if (tid == 0) {
    float l0 = bg[0], l1 = bg[1];
    for (int w = 0; w < 8; ++w) { l0 += lred[w]; l1 += lred[8 + w]; }
    const float mx = fmaxf(l0, l1);
    const float e0 = expf(l0 - mx), e1 = expf(l1 - mx);
    gw[0] = e0 / (e0 + e1);
    gw[1] = e1 / (e0 + e1);
  }
  __syncthreads();
  const int h = tid;
  float aa = bu_a[h], ab = bu_b[h];
  for (int i = 0; i < 1024; ++i) aa = fmaf(gin[i], Wu_a[i * H + h], aa);
  for (int i = 0; i < 1024; ++i) {
    const float x = (i < 512) ? gin[i] : gin[i + 512];
    ab = fmaf(x, Wu_b[i * H + h], ab);
  }
  att[b * H + h] = gw[0] * tanhf(aa) + gw[1] * tanhf(ab);
}

extern "C" void kernel_launch(void* const* d_in, const int* in_sizes, int n_in,
                              void* d_out, int out_size, void* d_ws, size_t ws_size,
                              hipStream_t stream) {
  const float* query    = (const float*)d_in[0];
  const float* values_a = (const float*)d_in[1];
  const float* values_b = (const float*)d_in[2];
  const int*   mask_a   = (const int*)d_in[3];
  const int*   mask_b   = (const int*)d_in[4];
  const float* Wk_a = (const float*)d_in[5];
  const float* Wq_a = (const float*)d_in[6];
  const float* v_a  = (const float*)d_in[7];
  const float* Wk_b = (const float*)d_in[8];
  const float* Wq_b = (const float*)d_in[9];
  const float* v_b  = (const float*)d_in[10];
  const float* Wg   = (const float*)d_in[11];
  const float* bg   = (const float*)d_in[12];
  const float* Wu_a = (const float*)d_in[13];
  const float* bu_a = (const float*)d_in[14];
  const float* Wu_b = (const float*)d_in[15];
  const float* bu_b = (const float*)d_in[16];
  float* out = (float*)d_out;

  float* wsf    = (float*)d_ws;
  float* qproj  = wsf;                        // [2][B][H]   = 32768 f
  float* scores = wsf + 2 * B * H;            // [2][B][S]   = 262144 f
  float* ctx    = wsf + 2 * B * H + 2 * B * S;// [2][B][K]   = 32768 f

  qproj_kernel<<<dim3(B, 2), 512, 0, stream>>>(query, Wq_a, Wq_b, qproj);
  scores_kernel<<<dim3(S / 64, B, 2), 256, 0, stream>>>(
      values_a, values_b, Wk_a, Wk_b, v_a, v_b, mask_a, mask_b, qproj, scores);
  sparsemax_kernel<<<dim3(B, 2), 1024, 0, stream>>>(scores, out);
  context_kernel<<<dim3(B, 2), 512, 0, stream>>>(values_a, values_b, out, ctx);
  merge_kernel<<<B, 512, 0, stream>>>(query, ctx, Wg, bg, Wu_a, bu_a, Wu_b, bu_b, out);
}

// Round 2
// 1177.776 us; speedup vs baseline: 2.1589x; 2.1589x over previous
//
#include <hip/hip_runtime.h>
#include <math.h>

#define NEGV (-1e9f)
constexpr int B = 32, S = 4096, K = 512, H = 512;

typedef __attribute__((ext_vector_type(8))) short bf16x8;
typedef __attribute__((ext_vector_type(4))) float f32x4;

__device__ __forceinline__ short f2bf(float x) {
  union { float f; unsigned u; } v; v.f = x;
  unsigned r = (v.u + 0x7FFFu + ((v.u >> 16) & 1u)) >> 16;
  return (short)r;
}

#define GLOAD_LDS16(g, s) \
  __builtin_amdgcn_global_load_lds((const __attribute__((address_space(1))) unsigned int*)(g), \
                                   (__attribute__((address_space(3))) unsigned int*)(s), 16, 0, 0)

// ---------------- K0: pre-swizzle Wk (f32) -> bf16 MFMA-B-fragment-major layout
// Layout per head: frag index f = (c*32 + n)*64 + lane, 8 bf16 (16 B) each.
//   c = k-chunk (K/32), n = h-tile (H/16), lane: B[k=c*32+(lane>>4)*8+j][h=n*16+(lane&15)]
__global__ __launch_bounds__(64)
void wkswizzle_kernel(const float* __restrict__ Wk_a, const float* __restrict__ Wk_b,
                      short* __restrict__ WkT) {
  const int head = blockIdx.y;
  const float* __restrict__ Wk = head ? Wk_b : Wk_a;
  const int cn = blockIdx.x;            // 0..511 : c*32+n
  const int c = cn >> 5, n = cn & 31;
  const int l = threadIdx.x;
  const int kb = c * 32 + ((l >> 4) << 3);
  const int h = n * 16 + (l & 15);
  bf16x8 frag;
#pragma unroll
  for (int j = 0; j < 8; ++j) frag[j] = f2bf(Wk[(size_t)(kb + j) * H + h]);
  *(bf16x8*)(WkT + (size_t)head * 262144 + ((size_t)cn * 64 + l) * 8) = frag;
}

// ---------------- K1: qproj[head][b][h] = query[b] @ Wq_head ----------------
__global__ __launch_bounds__(512)
void qproj_kernel(const float* __restrict__ query,
                  const float* __restrict__ Wq_a,
                  const float* __restrict__ Wq_b,
                  float* __restrict__ qproj) {
  const int b = blockIdx.x, head = blockIdx.y;
  const float* __restrict__ Wq = head ? Wq_b : Wq_a;
  __shared__ float qs[H];
  qs[threadIdx.x] = query[b * H + threadIdx.x];
  __syncthreads();
  const int h = threadIdx.x;
  float acc = 0.f;
#pragma unroll 8
  for (int k = 0; k < H; ++k) acc = fmaf(qs[k], Wq[k * H + h], acc);
  qproj[(head * B + b) * H + h] = acc;
}

// ---------------- K2: scores via bf16 MFMA. Block 256 (4 waves), tile 64s x 512h.
// Wave w covers s 0..63 x h [w*128, w*128+128) as 4(s) x 8(h) tiles of 16x16.
__global__ __launch_bounds__(256)
void scores_mfma_kernel(const float* __restrict__ values_a, const float* __restrict__ values_b,
                        const short* __restrict__ WkT,
                        const float* __restrict__ v_a, const float* __restrict__ v_b,
                        const int* __restrict__ mask_a, const int* __restrict__ mask_b,
                        const float* __restrict__ qproj,
                        float* __restrict__ scores) {
  const int head = blockIdx.z, b = blockIdx.y, s0 = blockIdx.x * 64;
  const float* __restrict__ V  = (head ? values_b : values_a) + (size_t)b * S * K;
  const float* __restrict__ v  = head ? v_b : v_a;
  const int*   __restrict__ mask = (head ? mask_b : mask_a) + b * S;
  const float* __restrict__ qp = qproj + (head * B + b) * H;
  const short* __restrict__ wkb = WkT + (size_t)head * 262144;

  __shared__ __align__(16) short Alds[4 * 64 * 8];      // 4 KB  : [s-tile][lane][8]
  __shared__ __align__(16) short Blds[32 * 64 * 8];     // 32 KB : [n-tile(global)][lane][8]
  __shared__ float red[4 * 64];                          // 1 KB

  const int tid = threadIdx.x;
  const int w = tid >> 6, l = tid & 63;

  // A staging indices: thread t loads V[s0 + (t>>2)][k0 + (t&3)*8 .. +7]
  const int sa = tid >> 2;
  const int ksub = tid & 3;
  const int fl = (sa & 15) | (ksub << 4);
  short* const awr = Alds + ((sa >> 4) * 64 + fl) * 8;
  const float* const arow = V + (size_t)(s0 + sa) * K + ksub * 8;

  // per-lane h-parameters for the epilogue
  float qpr[8], vr[8];
#pragma unroll
  for (int n = 0; n < 8; ++n) {
    const int h = w * 128 + n * 16 + (l & 15);
    qpr[n] = qp[h];
    vr[n] = v[h];
  }

  f32x4 acc[4][8] = {};

  for (int c = 0; c < 16; ++c) {
    const float4 p0 = *(const float4*)(arow + c * 32);
    const float4 p1 = *(const float4*)(arow + c * 32 + 4);
    __syncthreads();   // protect A/B LDS from previous iteration's readers
    bf16x8 af;
    af[0] = f2bf(p0.x); af[1] = f2bf(p0.y); af[2] = f2bf(p0.z); af[3] = f2bf(p0.w);
    af[4] = f2bf(p1.x); af[5] = f2bf(p1.y); af[6] = f2bf(p1.z); af[7] = f2bf(p1.w);
    *(bf16x8*)awr = af;
#pragma unroll
    for (int nl = 0; nl < 8; ++nl) {
      const int nt = w * 8 + nl;
      GLOAD_LDS16(wkb + ((size_t)(c * 32 + nt) * 64 + l) * 8, Blds + (size_t)nt * 512);
    }
    __syncthreads();   // drains vmcnt (B) + lgkm (A writes)
    bf16x8 afr[4];
#pragma unroll
    for (int i = 0; i < 4; ++i) afr[i] = *(const bf16x8*)(Alds + (i * 64 + l) * 8);
#pragma unroll
    for (int nl = 0; nl < 8; ++nl) {
      const bf16x8 bfr = *(const bf16x8*)(Blds + ((w * 8 + nl) * 64 + l) * 8);
#pragma unroll
      for (int i = 0; i < 4; ++i)
        acc[i][nl] = __builtin_amdgcn_mfma_f32_16x16x32_bf16(afr[i], bfr, acc[i][nl], 0, 0, 0);
    }
  }

  // Epilogue: score_contrib = sum_h v[h] * tanh(acc + qp[h])
  // C/D layout: col(h) = lane&15, row(s within tile) = (lane>>4)*4 + reg
  float part[4][4];
#pragma unroll
  for (int i = 0; i < 4; ++i)
#pragma unroll
    for (int r = 0; r < 4; ++r) {
      float p = 0.f;
#pragma unroll
      for (int n = 0; n < 8; ++n) p = fmaf(vr[n], tanhf(acc[i][n][r] + qpr[n]), p);
#pragma unroll
      for (int off = 8; off > 0; off >>= 1) p += __shfl_xor(p, off, 64);
      part[i][r] = p;
    }
  if ((l & 15) == 0) {
#pragma unroll
    for (int i = 0; i < 4; ++i)
#pragma unroll
      for (int r = 0; r < 4; ++r)
        red[w * 64 + i * 16 + (l >> 4) * 4 + r] = part[i][r];
  }
  __syncthreads();
  if (tid < 64) {
    const float tot = red[tid] + red[64 + tid] + red[128 + tid] + red[192 + tid];
    const int s = s0 + tid;
    scores[((size_t)head * B + b) * S + s] = mask[s] ? tot : NEGV;
  }
}

// ---------------- K3: sparsemax per (b, head) row via bisection + exact refine
__device__ __forceinline__ float block_reduce_1024(float v, float* lds, const bool is_max) {
#pragma unroll
  for (int o = 32; o > 0; o >>= 1) {
    const float other = __shfl_xor(v, o, 64);
    v = is_max ? fmaxf(v, other) : (v + other);
  }
  const int wid = threadIdx.x >> 6;
  __syncthreads();
  if ((threadIdx.x & 63) == 0) lds[wid] = v;
  __syncthreads();
  if (threadIdx.x == 0) {
    float r = lds[0];
    for (int w = 1; w < 16; ++w) r = is_max ? fmaxf(r, lds[w]) : (r + lds[w]);
    lds[0] = r;
  }
  __syncthreads();
  return lds[0];
}

__global__ __launch_bounds__(1024)
void sparsemax_kernel(const float* __restrict__ scores, float* __restrict__ d_out_f) {
  const int b = blockIdx.x, head = blockIdx.y;
  const float* __restrict__ z = scores + ((size_t)head * B + b) * S;
  float* __restrict__ alpha = d_out_f + B * H + (size_t)head * B * S + (size_t)b * S;
  __shared__ float lds[16];
  const int tid = threadIdx.x;
  float e[4];
#pragma unroll
  for (int t = 0; t < 4; ++t) e[t] = z[t * 1024 + tid];
  float m = fmaxf(fmaxf(e[0], e[1]), fmaxf(e[2], e[3]));
  m = block_reduce_1024(m, lds, true);
  float lo = m - 1.f, hi = m;
  for (int it = 0; it < 28; ++it) {
    const float mid = 0.5f * (lo + hi);
    float s = 0.f;
#pragma unroll
    for (int t = 0; t < 4; ++t) s += fmaxf(e[t] - mid, 0.f);
    s = block_reduce_1024(s, lds, false);
    if (s >= 1.f) lo = mid; else hi = mid;
  }
  float cnt = 0.f, sum = 0.f;
#pragma unroll
  for (int t = 0; t < 4; ++t) {
    if (e[t] > lo) { cnt += 1.f; sum += e[t]; }
  }
  cnt = block_reduce_1024(cnt, lds, false);
  sum = block_reduce_1024(sum, lds, false);
  const float tau = (sum - 1.f) / cnt;
#pragma unroll
  for (int t = 0; t < 4; ++t) alpha[t * 1024 + tid] = fmaxf(e[t] - tau, 0.f);
}

// ---------------- K4: context = alphas @ values, exploiting sparsemax sparsity
__global__ __launch_bounds__(512)
void context_kernel(const float* __restrict__ values_a, const float* __restrict__ values_b,
                    const float* __restrict__ d_out_f, float* __restrict__ ctx) {
  const int b = blockIdx.x, head = blockIdx.y;
  const float* __restrict__ V = (head ? values_b : values_a) + (size_t)b * S * K;
  const float* __restrict__ al = d_out_f + B * H + (size_t)head * B * S + (size_t)b * S;
  __shared__ int cnt;
  __shared__ int sidx[S];
  __shared__ float sal[S];
  if (threadIdx.x == 0) cnt = 0;
  __syncthreads();
  for (int i = threadIdx.x; i < S; i += 512) {
    const float a = al[i];
    if (a > 0.f) { const int p = atomicAdd(&cnt, 1); sidx[p] = i; sal[p] = a; }
  }
  __syncthreads();
  const int n = cnt;
  const int j = threadIdx.x;
  float acc = 0.f;
  for (int t = 0; t < n; ++t) acc = fmaf(sal[t], V[(size_t)sidx[t] * K + j], acc);
  ctx[(head * B + b) * K + j] = acc;
}

// ---------------- K5: gate + candidates + output merge, one block per batch
__global__ __launch_bounds__(512)
void merge_kernel(const float* __restrict__ query, const float* __restrict__ ctx,
                  const float* __restrict__ Wg, const float* __restrict__ bg,
                  const float* __restrict__ Wu_a, const float* __restrict__ bu_a,
                  const float* __restrict__ Wu_b, const float* __restrict__ bu_b,
                  float* __restrict__ att) {
  const int b = blockIdx.x;
  __shared__ float gin[1536];
  __shared__ float lred[16];
  __shared__ float gw[2];
  const int tid = threadIdx.x;
  gin[tid]        = query[b * H + tid];
  gin[512 + tid]  = ctx[(0 * B + b) * K + tid];
  gin[1024 + tid] = ctx[(1 * B + b) * K + tid];
  __syncthreads();
  float p0 = 0.f, p1 = 0.f;
  for (int i = tid; i < 1536; i += 512) {
    const float x = gin[i];
    p0 = fmaf(x, Wg[i * 2 + 0], p0);
    p1 = fmaf(x, Wg[i * 2 + 1], p1);
  }
#pragma unroll
  for (int o = 32; o > 0; o >>= 1) { p0 += __shfl_xor(p0, o, 64); p1 += __shfl_xor(p1, o, 64); }
  if ((tid & 63) == 0) { lred[tid >> 6] = p0; lred[8 + (tid >> 6)] = p1; }
  __syncthreads();
  if (tid == 0) {
    float l0 = bg[0], l1 = bg[1];
    for (int w = 0; w < 8; ++w) { l0 += lred[w]; l1 += lred[8 + w]; }
    const float mx = fmaxf(l0, l1);
    const float e0 = expf(l0 - mx), e1 = expf(l1 - mx);
    gw[0] = e0 / (e0 + e1);
    gw[1] = e1 / (e0 + e1);
  }
  __syncthreads();
  const int h = tid;
  float aa = bu_a[h], ab = bu_b[h];
  for (int i = 0; i < 1024; ++i) aa = fmaf(gin[i], Wu_a[i * H + h], aa);
  for (int i = 0; i < 1024; ++i) {
    const float x = (i < 512) ? gin[i] : gin[i + 512];
    ab = fmaf(x, Wu_b[i * H + h], ab);
  }
  att[b * H + h] = gw[0] * tanhf(aa) + gw[1] * tanhf(ab);
}

extern "C" void kernel_launch(void* const* d_in, const int* in_sizes, int n_in,
                              void* d_out, int out_size, void* d_ws, size_t ws_size,
                              hipStream_t stream) {
  const float* query    = (const float*)d_in[0];
  const float* values_a = (const float*)d_in[1];
  const float* values_b = (const float*)d_in[2];
  const int*   mask_a   = (const int*)d_in[3];
  const int*   mask_b   = (const int*)d_in[4];
  const float* Wk_a = (const float*)d_in[5];
  const float* Wq_a = (const float*)d_in[6];
  const float* v_a  = (const float*)d_in[7];
  const float* Wk_b = (const float*)d_in[8];
  const float* Wq_b = (const float*)d_in[9];
  const float* v_b  = (const float*)d_in[10];
  const float* Wg   = (const float*)d_in[11];
  const float* bg   = (const float*)d_in[12];
  const float* Wu_a = (const float*)d_in[13];
  const float* bu_a = (const float*)d_in[14];
  const float* Wu_b = (const float*)d_in[15];
  const float* bu_b = (const float*)d_in[16];
  float* out = (float*)d_out;

  float* wsf    = (float*)d_ws;
  float* qproj  = wsf;                                  // [2][B][H]
  float* scores = wsf + 2 * B * H;                      // [2][B][S]
  float* ctx    = wsf + 2 * B * H + 2 * B * S;          // [2][B][K]
  short* WkT    = (short*)(wsf + 2 * B * H + 2 * B * S + 2 * B * K);  // 2 x 262144 bf16

  wkswizzle_kernel<<<dim3(512, 2), 64, 0, stream>>>(Wk_a, Wk_b, WkT);
  qproj_kernel<<<dim3(B, 2), 512, 0, stream>>>(query, Wq_a, Wq_b, qproj);
  scores_mfma_kernel<<<dim3(S / 64, B, 2), 256, 0, stream>>>(
      values_a, values_b, WkT, v_a, v_b, mask_a, mask_b, qproj, scores);
  sparsemax_kernel<<<dim3(B, 2), 1024, 0, stream>>>(scores, out);
  context_kernel<<<dim3(B, 2), 512, 0, stream>>>(values_a, values_b, out, ctx);
  merge_kernel<<<B, 512, 0, stream>>>(query, ctx, Wg, bg, Wu_a, bu_a, Wu_b, bu_b, out);
}

// Round 3
// 887.593 us; speedup vs baseline: 2.8648x; 1.3269x over previous
//
#include <hip/hip_runtime.h>
#include <math.h>

#define NEGV (-1e9f)
constexpr int B = 32, S = 4096, K = 512, H = 512;

typedef __attribute__((ext_vector_type(8))) short bf16x8;
typedef __attribute__((ext_vector_type(4))) float f32x4;

__device__ __forceinline__ short f2bf(float x) {
  union { float f; unsigned u; } v; v.f = x;
  unsigned r = (v.u + 0x7FFFu + ((v.u >> 16) & 1u)) >> 16;
  return (short)r;
}

__device__ __forceinline__ float fast_tanh(float x) {
  // tanh(x) = 1 - 2/(exp(2x)+1); accurate to ~1e-6, saturates correctly
  return 1.f - 2.f / (__expf(2.f * x) + 1.f);
}

// ---------------- K0: pre-swizzle Wk (f32) -> bf16 MFMA-B-fragment-major layout
// frag f = (c*32 + n)*64 + lane; lane holds B[k=c*32+(lane>>4)*8+j][h=n*16+(lane&15)]
__global__ __launch_bounds__(64)
void wkswizzle_kernel(const float* __restrict__ Wk_a, const float* __restrict__ Wk_b,
                      short* __restrict__ WkT) {
  const int head = blockIdx.y;
  const float* __restrict__ Wk = head ? Wk_b : Wk_a;
  const int cn = blockIdx.x;            // 0..511 : c*32+n
  const int c = cn >> 5, n = cn & 31;
  const int l = threadIdx.x;
  const int kb = c * 32 + ((l >> 4) << 3);
  const int h = n * 16 + (l & 15);
  bf16x8 frag;
#pragma unroll
  for (int j = 0; j < 8; ++j) frag[j] = f2bf(Wk[(size_t)(kb + j) * H + h]);
  *(bf16x8*)(WkT + (size_t)head * 262144 + ((size_t)cn * 64 + l) * 8) = frag;
}

// ---------------- K1: qproj[head][b][h] = query[b] @ Wq_head ----------------
__global__ __launch_bounds__(512)
void qproj_kernel(const float* __restrict__ query,
                  const float* __restrict__ Wq_a,
                  const float* __restrict__ Wq_b,
                  float* __restrict__ qproj) {
  const int b = blockIdx.x, head = blockIdx.y;
  const float* __restrict__ Wq = head ? Wq_b : Wq_a;
  __shared__ float qs[H];
  qs[threadIdx.x] = query[b * H + threadIdx.x];
  __syncthreads();
  const int h = threadIdx.x;
  float acc = 0.f;
#pragma unroll 8
  for (int k = 0; k < H; ++k) acc = fmaf(qs[k], Wq[k * H + h], acc);
  qproj[(head * B + b) * H + h] = acc;
}

// ---------------- K2: partial scores via bf16 MFMA, barrier-light K-loop.
// Block 256 (4 waves), tile 64s x 256h (hslab). Wave w: s 0..63 x h-tiles [hslab*16+w*4, +4).
// B frags read straight from L2 (pre-swizzled WkT) into VGPRs — no LDS, no vmcnt@barrier.
// A (V) staged through a 2x4KB LDS double buffer; one lgkm-only barrier per K-chunk.
__global__ __launch_bounds__(256, 4)
void scores_mfma_kernel(const float* __restrict__ values_a, const float* __restrict__ values_b,
                        const short* __restrict__ WkT,
                        const float* __restrict__ v_a, const float* __restrict__ v_b,
                        const float* __restrict__ qproj,
                        float* __restrict__ scores_part) {
  const int head = blockIdx.z, b = blockIdx.y;
  const int s0 = (blockIdx.x >> 1) * 64;
  const int hslab = blockIdx.x & 1;
  const float* __restrict__ V  = (head ? values_b : values_a) + (size_t)b * S * K;
  const float* __restrict__ v  = head ? v_b : v_a;
  const float* __restrict__ qp = qproj + (head * B + b) * H;
  const short* __restrict__ wkb = WkT + (size_t)head * 262144;

  __shared__ __align__(16) short Albuf[2][4 * 64 * 8];   // 2 x 4 KB
  __shared__ float red[4 * 64];

  const int tid = threadIdx.x;
  const int w = tid >> 6, l = tid & 63;

  // A staging: thread t stages V[s0 + (t>>2)][c*32 + (t&3)*8 .. +7] as one b128 frag-line
  const int sa = tid >> 2, ka = (tid & 3) * 8;
  const float* const arow = V + (size_t)(s0 + sa) * K + ka;
  const int afrag = (sa >> 4) * 64 + ((sa & 15) | ((ka >> 3) << 4));
  // B frags: wave's h-tiles n = hslab*16 + w*4 + nl
  const short* const bbase = wkb + ((size_t)(hslab * 16 + w * 4) * 64 + l) * 8;

  f32x4 acc[4][4] = {};

  // prolog: stage chunk 0
  float4 p0 = *(const float4*)(arow);
  float4 p1 = *(const float4*)(arow + 4);
  {
    bf16x8 af;
    af[0] = f2bf(p0.x); af[1] = f2bf(p0.y); af[2] = f2bf(p0.z); af[3] = f2bf(p0.w);
    af[4] = f2bf(p1.x); af[5] = f2bf(p1.y); af[6] = f2bf(p1.z); af[7] = f2bf(p1.w);
    *(bf16x8*)(Albuf[0] + afrag * 8) = af;
  }
  int pb = 0;
  for (int c = 0; c < 16; ++c) {
    // prefetch next A granule (consumed at end of this iteration)
    if (c < 15) {
      p0 = *(const float4*)(arow + (c + 1) * 32);
      p1 = *(const float4*)(arow + (c + 1) * 32 + 4);
    }
    // B frag loads for this chunk — issued before the barrier so L2 latency overlaps it
    bf16x8 bfr[4];
#pragma unroll
    for (int nl = 0; nl < 4; ++nl)
      bfr[nl] = *(const bf16x8*)(bbase + ((size_t)c * 32 + nl) * 512);
    __syncthreads();   // lgkm-only: A writes of prev iter visible
    bf16x8 afr[4];
#pragma unroll
    for (int i = 0; i < 4; ++i) afr[i] = *(const bf16x8*)(Albuf[pb] + (i * 64 + l) * 8);
#pragma unroll
    for (int nl = 0; nl < 4; ++nl)
#pragma unroll
      for (int i = 0; i < 4; ++i)
        acc[i][nl] = __builtin_amdgcn_mfma_f32_16x16x32_bf16(afr[i], bfr[nl], acc[i][nl], 0, 0, 0);
    if (c < 15) {
      bf16x8 af;
      af[0] = f2bf(p0.x); af[1] = f2bf(p0.y); af[2] = f2bf(p0.z); af[3] = f2bf(p0.w);
      af[4] = f2bf(p1.x); af[5] = f2bf(p1.y); af[6] = f2bf(p1.z); af[7] = f2bf(p1.w);
      *(bf16x8*)(Albuf[pb ^ 1] + afrag * 8) = af;
      pb ^= 1;
    }
  }

  // Epilogue: partial_score = sum_{h in slab} v[h] * tanh(acc + qp[h])
  float qpr[4], vr[4];
#pragma unroll
  for (int nl = 0; nl < 4; ++nl) {
    const int h = (hslab * 16 + w * 4 + nl) * 16 + (l & 15);
    qpr[nl] = qp[h];
    vr[nl] = v[h];
  }
#pragma unroll
  for (int i = 0; i < 4; ++i)
#pragma unroll
    for (int r = 0; r < 4; ++r) {
      float p = 0.f;
#pragma unroll
      for (int nl = 0; nl < 4; ++nl) p = fmaf(vr[nl], fast_tanh(acc[i][nl][r] + qpr[nl]), p);
#pragma unroll
      for (int off = 8; off > 0; off >>= 1) p += __shfl_xor(p, off, 64);
      if ((l & 15) == 0) red[w * 64 + i * 16 + (l >> 4) * 4 + r] = p;
    }
  __syncthreads();
  if (tid < 64) {
    const float tot = red[tid] + red[64 + tid] + red[128 + tid] + red[192 + tid];
    scores_part[(((size_t)hslab * 2 + head) * B + b) * S + s0 + tid] = tot;
  }
}

// ---------------- K3: sparsemax (merges hslab partials + mask) ----------------
__device__ __forceinline__ float bred256(float v, const bool is_max, float* lds) {
#pragma unroll
  for (int o = 32; o > 0; o >>= 1) {
    const float t = __shfl_xor(v, o, 64);
    v = is_max ? fmaxf(v, t) : (v + t);
  }
  __syncthreads();                       // protect lds from previous call's readers
  if ((threadIdx.x & 63) == 0) lds[threadIdx.x >> 6] = v;
  __syncthreads();
  return is_max ? fmaxf(fmaxf(lds[0], lds[1]), fmaxf(lds[2], lds[3]))
                : (lds[0] + lds[1]) + (lds[2] + lds[3]);
}

__global__ __launch_bounds__(256)
void sparsemax_kernel(const float* __restrict__ scores_part,
                      const int* __restrict__ mask_a, const int* __restrict__ mask_b,
                      float* __restrict__ d_out_f) {
  const int b = blockIdx.x, head = blockIdx.y;
  const float* __restrict__ z0 = scores_part + (((size_t)0 * 2 + head) * B + b) * S;
  const float* __restrict__ z1 = scores_part + (((size_t)1 * 2 + head) * B + b) * S;
  const int* __restrict__ mask = (head ? mask_b : mask_a) + b * S;
  float* __restrict__ alpha = d_out_f + B * H + (size_t)head * B * S + (size_t)b * S;
  __shared__ float lds[4];
  const int tid = threadIdx.x;
  float e[16];
#pragma unroll
  for (int t = 0; t < 16; ++t) {
    const int s = t * 256 + tid;
    e[t] = mask[s] ? (z0[s] + z1[s]) : NEGV;
  }
  float m = NEGV;
#pragma unroll
  for (int t = 0; t < 16; ++t) m = fmaxf(m, e[t]);
  m = bred256(m, true, lds);
  float lo = m - 1.f, hi = m;
  for (int it = 0; it < 28; ++it) {
    const float mid = 0.5f * (lo + hi);
    float s = 0.f;
#pragma unroll
    for (int t = 0; t < 16; ++t) s += fmaxf(e[t] - mid, 0.f);
    s = bred256(s, false, lds);
    if (s >= 1.f) lo = mid; else hi = mid;
  }
  float cnt = 0.f, sum = 0.f;
#pragma unroll
  for (int t = 0; t < 16; ++t) {
    if (e[t] > lo) { cnt += 1.f; sum += e[t]; }
  }
  cnt = bred256(cnt, false, lds);
  sum = bred256(sum, false, lds);
  const float tau = (sum - 1.f) / cnt;
#pragma unroll
  for (int t = 0; t < 16; ++t) alpha[t * 256 + tid] = fmaxf(e[t] - tau, 0.f);
}

// ---------------- K4: context = alphas @ values, exploiting sparsemax sparsity
__global__ __launch_bounds__(512)
void context_kernel(const float* __restrict__ values_a, const float* __restrict__ values_b,
                    const float* __restrict__ d_out_f, float* __restrict__ ctx) {
  const int b = blockIdx.x, head = blockIdx.y;
  const float* __restrict__ V = (head ? values_b : values_a) + (size_t)b * S * K;
  const float* __restrict__ al = d_out_f + B * H + (size_t)head * B * S + (size_t)b * S;
  __shared__ int cnt;
  __shared__ int sidx[S];
  __shared__ float sal[S];
  if (threadIdx.x == 0) cnt = 0;
  __syncthreads();
  for (int i = threadIdx.x; i < S; i += 512) {
    const float a = al[i];
    if (a > 0.f) { const int p = atomicAdd(&cnt, 1); sidx[p] = i; sal[p] = a; }
  }
  __syncthreads();
  const int n = cnt;
  const int j = threadIdx.x;
  float acc = 0.f;
  for (int t = 0; t < n; ++t) acc = fmaf(sal[t], V[(size_t)sidx[t] * K + j], acc);
  ctx[(head * B + b) * K + j] = acc;
}

// ---------------- K5: gate + candidates + output merge, one block per batch
__global__ __launch_bounds__(512)
void merge_kernel(const float* __restrict__ query, const float* __restrict__ ctx,
                  const float* __restrict__ Wg, const float* __restrict__ bg,
                  const float* __restrict__ Wu_a, const float* __restrict__ bu_a,
                  const float* __restrict__ Wu_b, const float* __restrict__ bu_b,
                  float* __restrict__ att) {
  const int b = blockIdx.x;
  __shared__ float gin[1536];
  __shared__ float lred[16];
  __shared__ float gw[2];
  const int tid = threadIdx.x;
  gin[tid]        = query[b * H + tid];
  gin[512 + tid]  = ctx[(0 * B + b) * K + tid];
  gin[1024 + tid] = ctx[(1 * B + b) * K + tid];
  __syncthreads();
  float p0 = 0.f, p1 = 0.f;
  for (int i = tid; i < 1536; i += 512) {
    const float x = gin[i];
    p0 = fmaf(x, Wg[i * 2 + 0], p0);
    p1 = fmaf(x, Wg[i * 2 + 1], p1);
  }
#pragma unroll
  for (int o = 32; o > 0; o >>= 1) { p0 += __shfl_xor(p0, o, 64); p1 += __shfl_xor(p1, o, 64); }
  if ((tid & 63) == 0) { lred[tid >> 6] = p0; lred[8 + (tid >> 6)] = p1; }
  __syncthreads();
  if (tid == 0) {
    float l0 = bg[0], l1 = bg[1];
    for (int w = 0; w < 8; ++w) { l0 += lred[w]; l1 += lred[8 + w]; }
    const float mx = fmaxf(l0, l1);
    const float e0 = expf(l0 - mx), e1 = expf(l1 - mx);
    gw[0] = e0 / (e0 + e1);
    gw[1] = e1 / (e0 + e1);
  }
  __syncthreads();
  const int h = tid;
  float aa = bu_a[h], ab = bu_b[h];
  for (int i = 0; i < 1024; ++i) aa = fmaf(gin[i], Wu_a[i * H + h], aa);
  for (int i = 0; i < 1024; ++i) {
    const float x = (i < 512) ? gin[i] : gin[i + 512];
    ab = fmaf(x, Wu_b[i * H + h], ab);
  }
  att[b * H + h] = gw[0] * tanhf(aa) + gw[1] * tanhf(ab);
}

extern "C" void kernel_launch(void* const* d_in, const int* in_sizes, int n_in,
                              void* d_out, int out_size, void* d_ws, size_t ws_size,
                              hipStream_t stream) {
  const float* query    = (const float*)d_in[0];
  const float* values_a = (const float*)d_in[1];
  const float* values_b = (const float*)d_in[2];
  const int*   mask_a   = (const int*)d_in[3];
  const int*   mask_b   = (const int*)d_in[4];
  const float* Wk_a = (const float*)d_in[5];
  const float* Wq_a = (const float*)d_in[6];
  const float* v_a  = (const float*)d_in[7];
  const float* Wk_b = (const float*)d_in[8];
  const float* Wq_b = (const float*)d_in[9];
  const float* v_b  = (const float*)d_in[10];
  const float* Wg   = (const float*)d_in[11];
  const float* bg   = (const float*)d_in[12];
  const float* Wu_a = (const float*)d_in[13];
  const float* bu_a = (const float*)d_in[14];
  const float* Wu_b = (const float*)d_in[15];
  const float* bu_b = (const float*)d_in[16];
  float* out = (float*)d_out;

  float* wsf         = (float*)d_ws;
  float* qproj       = wsf;                                   // [2][B][H]      32K f
  float* scores_part = wsf + 2 * B * H;                       // [2][2][B][S]  512K f
  float* ctx         = wsf + 2 * B * H + 4 * B * S;           // [2][B][K]      32K f
  short* WkT         = (short*)(wsf + 2 * B * H + 4 * B * S + 2 * B * K);  // 2 x 262144 bf16

  wkswizzle_kernel<<<dim3(512, 2), 64, 0, stream>>>(Wk_a, Wk_b, WkT);
  qproj_kernel<<<dim3(B, 2), 512, 0, stream>>>(query, Wq_a, Wq_b, qproj);
  scores_mfma_kernel<<<dim3(128, B, 2), 256, 0, stream>>>(
      values_a, values_b, WkT, v_a, v_b, qproj, scores_part);
  sparsemax_kernel<<<dim3(B, 2), 256, 0, stream>>>(scores_part, mask_a, mask_b, out);
  context_kernel<<<dim3(B, 2), 512, 0, stream>>>(values_a, values_b, out, ctx);
  merge_kernel<<<B, 512, 0, stream>>>(query, ctx, Wg, bg, Wu_a, bu_a, Wu_b, bu_b, out);
}